// Round 11
// baseline (330.972 us; speedup 1.0000x reference)
//
#include <hip/hip_runtime.h>
#include <hip/hip_bf16.h>
#include <hip/hip_cooperative_groups.h>
#include <stdint.h>

namespace cg = cooperative_groups;

#define B_DIM   4096
#define IN_DIM  512
#define OUT_DIM 512
#define M_DIM   16
#define K_DIM   (IN_DIM * M_DIM)     // 8192
#define MN      (B_DIM * OUT_DIM)    // 2097152

typedef unsigned short ushort_t;
typedef __attribute__((ext_vector_type(8))) __bf16 bf16x8;
typedef __attribute__((ext_vector_type(2))) __bf16 bf16x2;
typedef __attribute__((ext_vector_type(4))) float  f32x4;

__device__ __forceinline__ ushort_t f2bf(float f) {
  union { float f; uint32_t u; } v; v.f = f;
  uint32_t u = v.u + 0x7fffu + ((v.u >> 16) & 1u);   // RNE
  return (ushort_t)(u >> 16);
}

// pack two floats -> one u32 of 2 x bf16 (compiler emits v_cvt_pk_bf16_f32)
__device__ __forceinline__ uint32_t pkbf(float lo, float hi) {
  union { bf16x2 h; uint32_t u; } v;
  v.h[0] = (__bf16)lo; v.h[1] = (__bf16)hi;
  return v.u;
}

// force a wave-uniform float into an SGPR
__device__ __forceinline__ float rfl(float f) {
  union { float f; int i; } v; v.f = f;
  v.i = __builtin_amdgcn_readfirstlane(v.i);
  return v.f;
}

// ---------- fused single-launch kernel: convert + basis/GEMM + splitK-reduce ----------
#define BM 128
#define BN 512
#define BK 32                 // = 2 input-columns x 16 m
#define SPLITK 8
#define KC (K_DIM / SPLITK)   // 1024
#define NITER (KC / BK)       // 32 K-steps
#define XCOLS (KC / M_DIM)    // 64 x-columns per block
#define XPAD  129             // row-dim pad for conflict-free reads
#define NBLK  ((B_DIM / BM) * SPLITK)   // 256 blocks = 1/CU (LDS-bound) = #CUs
#define NTHR  (NBLK * 512)              // 131072 threads

#define GLD16(g, l) \
  __builtin_amdgcn_global_load_lds((const __attribute__((address_space(1))) void*)(g), \
                                   (__attribute__((address_space(3))) void*)(l), 16, 0, 0)

// fused counted-wait + barrier in ONE asm: memory ops cannot cross ("memory"
// clobber), but register-only VALU/MFMA remain schedulable around it.
#define WAIT_BAR(N) \
  asm volatile("s_waitcnt vmcnt(" #N ") lgkmcnt(0)\n\ts_barrier" ::: "memory")

template <int ATOMIC>
__global__ __launch_bounds__(512, 2) void gemm_fused(
    const float* __restrict__ x,      // [B_DIM][IN_DIM] fp32
    const float* __restrict__ coeffs, // [OUT][IN][M] fp32
    const float* __restrict__ bc,     // [16][8]
    ushort_t* coefb,                  // ws: coeffs bf16 [OUT_DIM][K_DIM]
    float* __restrict__ P,            // ws: partials [SPLITK][B][OUT]
    float* outF) {                    // final out [B][OUT]
  // LDS: As dbuf 16K + Bs TRIBUF 96K + Xs 32.25K = 144.25 KiB (1 block/CU)
  __shared__ __align__(16) ushort_t As[2][BM * BK];
  __shared__ __align__(16) ushort_t Bs[3][BN * BK];
  __shared__ __align__(16) float    Xs[XCOLS * XPAD];
  const int tid  = threadIdx.x;
  const int wave = tid >> 6;
  const int lane = tid & 63;
  const int wgid = blockIdx.x;
  const int ks = wgid & 7, bm = wgid >> 3;   // same-ks blocks -> same XCD, B-slice L2-hot
  cg::grid_group grid = cg::this_grid();

  // ================= phase A: coeffs fp32 -> bf16 (full grid) =================
  {
    const int gtid = wgid * 512 + tid;
    const float4* s4 = (const float4*)coeffs;
    ushort4* d4 = (ushort4*)coefb;
    #pragma unroll
    for (int j = 0; j < 8; ++j) {                 // 8 * 131072 = OUT*K/4
      int i = gtid + j * NTHR;
      float4 v = s4[i];
      ushort4 o;
      o.x = f2bf(v.x); o.y = f2bf(v.y); o.z = f2bf(v.z); o.w = f2bf(v.w);
      d4[i] = o;
    }
    if (ATOMIC) {                                 // zero output (replaces memset)
      float4* o4 = (float4*)outF;
      #pragma unroll
      for (int j = 0; j < 4; ++j)
        o4[gtid + j * NTHR] = make_float4(0.f, 0.f, 0.f, 0.f);
    }
  }
  __threadfence();
  grid.sync();    // coefb (and zeroed out) visible device-wide

  // ================= phase B: fused basis + GEMM (r9 core) =================
  // ---- x-tile staging (one-time): coalesced float4 loads -> transposed LDS ----
  {
    const int r = tid >> 2, q = tid & 3;
    const float4* xrow = (const float4*)(x + (size_t)(bm * BM + r) * IN_DIM + ks * XCOLS);
    #pragma unroll
    for (int j = 0; j < 4; ++j) {
      float4 v = xrow[q * 4 + j];
      Xs[(q * 16 + j * 4 + 0) * XPAD + r] = v.x;
      Xs[(q * 16 + j * 4 + 1) * XPAD + r] = v.y;
      Xs[(q * 16 + j * 4 + 2) * XPAD + r] = v.z;
      Xs[(q * 16 + j * 4 + 3) * XPAD + r] = v.w;
    }
  }

  // ---- B staging: global_load_lds linear dest, pre-swizzled source slot ----
  const ushort_t* Bt = coefb;
  const int srow = wave * 16 + (lane >> 2);
  const int scol = (((lane & 3) ^ ((lane >> 3) & 3)) * 8);
  const ushort_t* Bg0 = Bt + (size_t)srow * K_DIM + ks * KC + scol;
  const ushort_t* Bg1 = Bg0 + (size_t)128 * K_DIM;
  const ushort_t* Bg2 = Bg0 + (size_t)256 * K_DIM;
  const ushort_t* Bg3 = Bg0 + (size_t)384 * K_DIM;
  const int bofs0 = (wave * 16) * BK;
  const int bofs1 = (128 + wave * 16) * BK;
  const int bofs2 = (256 + wave * 16) * BK;
  const int bofs3 = (384 + wave * 16) * BK;

#define STAGEB(lb) do { \
    GLD16(Bg0, &Bs[lb][bofs0]); GLD16(Bg1, &Bs[lb][bofs1]); \
    GLD16(Bg2, &Bs[lb][bofs2]); GLD16(Bg3, &Bs[lb][bofs3]); \
    Bg0 += BK; Bg1 += BK; Bg2 += BK; Bg3 += BK; } while (0)

  // ---- basis production: thread -> (row, i_local, m-half), half wave-uniform ----
  const int half = wave & 1;                       // m in [half*8, half*8+8)
  const int arow = (wave >> 1) * 32 + (lane >> 1); // 0..127
  const int il   = lane & 1;                       // which of 2 input cols in BK
  const int aslot = ((il * 2 + half) ^ ((lane >> 2) & 3));  // XOR-swizzled 16B slot
  const int awe   = arow * BK + aslot * 8;
  const int xbase = il * XPAD + arow;              // Xs[(il+2t)*XPAD + arow]

  const float LOG2E = 1.44269504088896340736f;
  const float LN2   = 0.69314718055994530942f;
  // c1,c2 pre-scaled by LN2 (saves 2 v_mul per eval); kept SGPR via re-readfirstlane
  float c1[8], c2[8], c3[8], c4[8], c5[8], c6[8], c7[8], c8[8];
  {
    const float* bch = bc + half * 64;
    #pragma unroll
    for (int m = 0; m < 8; ++m) {
      c1[m] = rfl(rfl(bch[m*8+0]) * LN2); c2[m] = rfl(rfl(bch[m*8+1]) * LN2);
      c3[m] = rfl(bch[m*8+2]); c4[m] = rfl(bch[m*8+3]);
      c5[m] = rfl(bch[m*8+4]); c6[m] = rfl(bch[m*8+5]);
      c7[m] = rfl(bch[m*8+6]); c8[m] = rfl(bch[m*8+7]);
    }
  }

#define BASIS(ab, t) do { \
    float xv = Xs[xbase + 2 * XPAD * (t)]; \
    float xl2 = xv * LOG2E; \
    float x2 = xv * xv, x3 = x2 * xv, x4 = x2 * x2; \
    float ym[8]; \
    _Pragma("unroll") \
    for (int mi = 0; mi < 8; ++mi) { \
      float e     = __builtin_amdgcn_exp2f(c3[mi] * xl2); \
      float inner = e - 1.0f; \
      float p     = __builtin_amdgcn_exp2f(c4[mi] * __builtin_amdgcn_logf(inner)); \
      float L1    = __builtin_amdgcn_logf(1.0f + p); \
      float vv    = __builtin_amdgcn_logf(1.0f + c2[mi] * L1); \
      ym[mi] = c1[mi] * vv + c5[mi] * xv + c6[mi] * x2 + c7[mi] * x3 + c8[mi] * x4; \
    } \
    *(uint4*)(&As[ab][awe]) = make_uint4(pkbf(ym[0], ym[1]), pkbf(ym[2], ym[3]), \
                                         pkbf(ym[4], ym[5]), pkbf(ym[6], ym[7])); \
  } while (0)

  // ---- MFMA geometry: 8 waves as 2x4 grid of 64x128 wave-tiles ----
  const int wr = wave >> 2, wc = wave & 3;
  const int fm = lane & 15;
  const int fkswz = (((lane >> 4) ^ ((lane >> 1) & 3)) << 3);

  f32x4 acc[4][8] = {};

#define COMPUTE(ab, lb) do { \
    bf16x8 af[4], bfv[8]; \
    _Pragma("unroll") \
    for (int t2 = 0; t2 < 4; ++t2) \
      af[t2] = *(const bf16x8*)&As[ab][(wr * 64 + t2 * 16 + fm) * BK + fkswz]; \
    _Pragma("unroll") \
    for (int u = 0; u < 8; ++u) \
      bfv[u] = *(const bf16x8*)&Bs[lb][(wc * 128 + u * 16 + fm) * BK + fkswz]; \
    __builtin_amdgcn_s_setprio(1); \
    _Pragma("unroll") \
    for (int mt = 0; mt < 4; ++mt) \
      _Pragma("unroll") \
      for (int nt = 0; nt < 8; ++nt) \
        acc[mt][nt] = __builtin_amdgcn_mfma_f32_16x16x32_bf16(af[mt], bfv[nt], acc[mt][nt], 0, 0, 0); \
    __builtin_amdgcn_s_setprio(0); \
  } while (0)

#define STEP(lbN, ap, ac, lb, t1) do { \
    STAGEB(lbN); BASIS(ap, t1); COMPUTE(ac, lb); WAIT_BAR(4); } while (0)

  // ---- prologue ----
  STAGEB(0); STAGEB(1);
  __syncthreads();              // Xs + Bs[0..1] visible (full drain, once)
  BASIS(0, 0);
  WAIT_BAR(0);                  // As[0] visible

  // ---- main loop: 30 steps, statically unrolled x6 (lb period 3, As parity 2) ----
  for (int tb = 0; tb < NITER - 2; tb += 6) {
    STEP(2, 1, 0, 0, tb + 1);   // t = tb+0
    STEP(0, 0, 1, 1, tb + 2);   // t = tb+1
    STEP(1, 1, 0, 2, tb + 3);   // t = tb+2
    STEP(2, 0, 1, 0, tb + 4);   // t = tb+3
    STEP(0, 1, 0, 1, tb + 5);   // t = tb+4
    STEP(1, 0, 1, 2, tb + 6);   // t = tb+5
  }
  // ---- tail K-steps: t = 30, 31 (all 32 batches already staged) ----
  BASIS(1, NITER - 1);
  COMPUTE(0, 0);                // t=30: As[0], Bs[0]
  WAIT_BAR(0);
  COMPUTE(1, 1);                // t=31: As[1], Bs[1]

  // ---- C-write: C/D layout col = lane&15, row = (lane>>4)*4 + reg ----
  const int colb = wc * 128 + fm;
  const int rowb = bm * BM + wr * 64 + (lane >> 4) * 4;
  float* dst = ATOMIC ? outF : (P + (size_t)ks * MN);
  #pragma unroll
  for (int mt = 0; mt < 4; ++mt) {
    #pragma unroll
    for (int nt = 0; nt < 8; ++nt) {
      #pragma unroll
      for (int j = 0; j < 4; ++j) {
        int row = rowb + mt * 16 + j;
        int col = colb + nt * 16;
        float vv = acc[mt][nt][j];
        if (ATOMIC) atomicAdd(dst + (size_t)row * OUT_DIM + col, vv);
        else        dst[(size_t)row * OUT_DIM + col] = vv;
      }
    }
  }

  // ================= phase C: split-K reduce (full grid) =================
  if (!ATOMIC) {
    __threadfence();            // release partials
    grid.sync();                // all partials written & visible device-wide
    const int gtid = wgid * 512 + tid;
    const float4* p4 = (const float4*)P;
    float4* o4 = (float4*)outF;
    #pragma unroll
    for (int j = 0; j < 4; ++j) {               // 4 * 131072 = MN/4
      size_t idx = (size_t)gtid + (size_t)j * NTHR;
      float4 r = p4[idx];
      #pragma unroll
      for (int s = 1; s < SPLITK; ++s) {        // fixed order == old reduce kernel
        float4 v = p4[idx + (size_t)s * (MN / 4)];
        r.x += v.x; r.y += v.y; r.z += v.z; r.w += v.w;
      }
      o4[idx] = r;
    }
  }
#undef STAGEB
#undef BASIS
#undef COMPUTE
#undef STEP
}

extern "C" void kernel_launch(void* const* d_in, const int* in_sizes, int n_in,
                              void* d_out, int out_size, void* d_ws, size_t ws_size,
                              hipStream_t stream) {
  const float* x      = (const float*)d_in[0];   // [4096][512]
  const float* coeffs = (const float*)d_in[1];   // [512][512][16]
  const float* b_coef = (const float*)d_in[2];   // [16][8]
  float* out = (float*)d_out;
  char*  ws  = (char*)d_ws;

  const size_t COEF_BYTES = (size_t)OUT_DIM * K_DIM * 2;   // 8 MiB
  const size_t PART_BYTES = (size_t)SPLITK * MN * 4;       // 64 MiB
  ushort_t* coefb = (ushort_t*)ws;
  float* partials = (float*)(ws + COEF_BYTES);
  const size_t FULL = COEF_BYTES + PART_BYTES;             // 72 MiB
  const bool use_atomic = (ws_size < FULL);   // deterministic per-session branch

  if (use_atomic) {
    void* args[] = { (void*)&x, (void*)&coeffs, (void*)&b_coef,
                     (void*)&coefb, (void*)&out, (void*)&out };
    hipLaunchCooperativeKernel((const void*)gemm_fused<1>,
                               dim3(NBLK), dim3(512), args, 0, stream);
  } else {
    void* args[] = { (void*)&x, (void*)&coeffs, (void*)&b_coef,
                     (void*)&coefb, (void*)&partials, (void*)&out };
    hipLaunchCooperativeKernel((const void*)gemm_fused<0>,
                               dim3(NBLK), dim3(512), args, 0, stream);
  }
}

// Round 12
// 136.755 us; speedup vs baseline: 2.4202x; 2.4202x over previous
//
#include <hip/hip_runtime.h>
#include <hip/hip_bf16.h>
#include <stdint.h>

#define B_DIM   4096
#define IN_DIM  512
#define OUT_DIM 512
#define M_DIM   16
#define K_DIM   (IN_DIM * M_DIM)     // 8192
#define MN      (B_DIM * OUT_DIM)    // 2097152

typedef unsigned short ushort_t;
typedef __attribute__((ext_vector_type(8))) __bf16 bf16x8;
typedef __attribute__((ext_vector_type(2))) __bf16 bf16x2;
typedef __attribute__((ext_vector_type(4))) float  f32x4;

__device__ __forceinline__ ushort_t f2bf(float f) {
  union { float f; uint32_t u; } v; v.f = f;
  uint32_t u = v.u + 0x7fffu + ((v.u >> 16) & 1u);   // RNE
  return (ushort_t)(u >> 16);
}

// pack two floats -> one u32 of 2 x bf16 (compiler emits v_cvt_pk_bf16_f32)
__device__ __forceinline__ uint32_t pkbf(float lo, float hi) {
  union { bf16x2 h; uint32_t u; } v;
  v.h[0] = (__bf16)lo; v.h[1] = (__bf16)hi;
  return v.u;
}

// force a wave-uniform float into an SGPR
__device__ __forceinline__ float rfl(float f) {
  union { float f; int i; } v; v.f = f;
  v.i = __builtin_amdgcn_readfirstlane(v.i);
  return v.f;
}

// ---------- phase 1: coeffs fp32 -> bf16 (layout [OUT][IN][M] == B^T [N][K]) ----------
#define CONV_N4 (OUT_DIM * K_DIM / 4)
__global__ __launch_bounds__(256) void convert_coeffs_kernel(
    const float* __restrict__ src, ushort_t* __restrict__ dst) {
  int i = blockIdx.x * 256 + threadIdx.x;
  float4 v = ((const float4*)src)[i];
  ushort4 o;
  o.x = f2bf(v.x); o.y = f2bf(v.y); o.z = f2bf(v.z); o.w = f2bf(v.w);
  ((ushort4*)dst)[i] = o;
}

// ---------- phase 2: FUSED basis+GEMM; producer-wave role split ----------
// BM=64/SPLITK=4: basis needs only 256 producer lanes/step -> waves 0-3 produce,
// waves 4-7 are pure-MFMA. SIMD s hosts waves {s, s+4}: the pure-MFMA wave
// overlaps the producer's transcendental chain (intra-SIMD role diversity
// WITHOUT duplicated schedule code — r4's spill trap avoided).
#define BM 64
#define BN 512
#define BK 32                 // = 2 input-columns x 16 m
#define SPLITK 4
#define KC (K_DIM / SPLITK)   // 2048
#define NITER (KC / BK)       // 64 K-steps
#define XCOLS (KC / M_DIM)    // 128 x-columns per block
#define XPAD  65              // row-dim pad (64 rows + 1)

#define GLD16(g, l) \
  __builtin_amdgcn_global_load_lds((const __attribute__((address_space(1))) void*)(g), \
                                   (__attribute__((address_space(3))) void*)(l), 16, 0, 0)

// fused counted-wait + barrier in ONE asm: memory ops cannot cross ("memory"
// clobber), but register-only VALU/MFMA remain schedulable around it.
#define WAIT_BAR(N) \
  asm volatile("s_waitcnt vmcnt(" #N ") lgkmcnt(0)\n\ts_barrier" ::: "memory")

template <int ATOMIC>
__global__ __launch_bounds__(512, 2) void gemm_kernel(
    const float* __restrict__ x,      // [B_DIM][IN_DIM] fp32
    const ushort_t* __restrict__ Bt,  // coeffs bf16 [OUT_DIM][K_DIM]
    const float* __restrict__ bc,     // [16][8]
    float* __restrict__ P) {          // partials [SPLITK][B][OUT] or out
  // LDS: As dbuf 8K + Bs TRIBUF 96K + Xs 32.5K = 136.5 KiB (1 block/CU)
  __shared__ __align__(16) ushort_t As[2][BM * BK];
  __shared__ __align__(16) ushort_t Bs[3][BN * BK];
  __shared__ __align__(16) float    Xs[XCOLS * XPAD];
  const int tid  = threadIdx.x;
  const int wave = tid >> 6;
  const int lane = tid & 63;
  const int wgid = blockIdx.x;
  const int ks = wgid & 3, bm = wgid >> 2;   // same-ks blocks -> 2 XCDs, 2MB B-slice L2-hot

  // ---- x-tile staging (one-time): coalesced float4 loads -> transposed LDS ----
  // thread t: row r = t>>3 (0..63), q = t&7 covers cols q*16 .. q*16+15
  {
    const int r = tid >> 3, q = tid & 7;
    const float4* xrow = (const float4*)(x + (size_t)(bm * BM + r) * IN_DIM + ks * XCOLS);
    #pragma unroll
    for (int j = 0; j < 4; ++j) {
      float4 v = xrow[q * 4 + j];
      Xs[(q * 16 + j * 4 + 0) * XPAD + r] = v.x;
      Xs[(q * 16 + j * 4 + 1) * XPAD + r] = v.y;
      Xs[(q * 16 + j * 4 + 2) * XPAD + r] = v.z;
      Xs[(q * 16 + j * 4 + 3) * XPAD + r] = v.w;
    }
  }

  // ---- B staging: global_load_lds linear dest, pre-swizzled source slot ----
  const int srow = wave * 16 + (lane >> 2);
  const int scol = (((lane & 3) ^ ((lane >> 3) & 3)) * 8);
  const ushort_t* Bg0 = Bt + (size_t)srow * K_DIM + ks * KC + scol;
  const ushort_t* Bg1 = Bg0 + (size_t)128 * K_DIM;
  const ushort_t* Bg2 = Bg0 + (size_t)256 * K_DIM;
  const ushort_t* Bg3 = Bg0 + (size_t)384 * K_DIM;
  const int bofs0 = (wave * 16) * BK;
  const int bofs1 = (128 + wave * 16) * BK;
  const int bofs2 = (256 + wave * 16) * BK;
  const int bofs3 = (384 + wave * 16) * BK;

  // lb is a compile-time constant at every use (static unroll)
#define STAGEB(lb) do { \
    GLD16(Bg0, &Bs[lb][bofs0]); GLD16(Bg1, &Bs[lb][bofs1]); \
    GLD16(Bg2, &Bs[lb][bofs2]); GLD16(Bg3, &Bs[lb][bofs3]); \
    Bg0 += BK; Bg1 += BK; Bg2 += BK; Bg3 += BK; } while (0)

  // ---- basis production (waves 0-3 only): thread -> (row, il, m-half) ----
  const int half = wave & 1;                       // m in [half*8, half*8+8)
  const int arow = (wave >> 1) * 32 + (lane >> 1); // 0..63 for waves 0-3
  const int il   = lane & 1;                       // which of 2 input cols in BK
  const int aslot = ((il * 2 + half) ^ ((lane >> 2) & 3));  // XOR-swizzled 16B slot
  const int awe   = arow * BK + aslot * 8;
  const int xbase = il * XPAD + arow;              // Xs[(il+2t)*XPAD + arow]

  const float LOG2E = 1.44269504088896340736f;
  const float LN2   = 0.69314718055994530942f;
  // c1,c2 pre-scaled by LN2; kept SGPR via re-readfirstlane
  float c1[8], c2[8], c3[8], c4[8], c5[8], c6[8], c7[8], c8[8];
  {
    const float* bch = bc + half * 64;
    #pragma unroll
    for (int m = 0; m < 8; ++m) {
      c1[m] = rfl(rfl(bch[m*8+0]) * LN2); c2[m] = rfl(rfl(bch[m*8+1]) * LN2);
      c3[m] = rfl(bch[m*8+2]); c4[m] = rfl(bch[m*8+3]);
      c5[m] = rfl(bch[m*8+4]); c6[m] = rfl(bch[m*8+5]);
      c7[m] = rfl(bch[m*8+6]); c8[m] = rfl(bch[m*8+7]);
    }
  }

#define BASIS(ab, t) do { \
    float xv = Xs[xbase + 2 * XPAD * (t)]; \
    float xl2 = xv * LOG2E; \
    float x2 = xv * xv, x3 = x2 * xv, x4 = x2 * x2; \
    float ym[8]; \
    _Pragma("unroll") \
    for (int mi = 0; mi < 8; ++mi) { \
      float e     = __builtin_amdgcn_exp2f(c3[mi] * xl2); \
      float inner = e - 1.0f; \
      float p     = __builtin_amdgcn_exp2f(c4[mi] * __builtin_amdgcn_logf(inner)); \
      float L1    = __builtin_amdgcn_logf(1.0f + p); \
      float vv    = __builtin_amdgcn_logf(1.0f + c2[mi] * L1); \
      ym[mi] = c1[mi] * vv + c5[mi] * xv + c6[mi] * x2 + c7[mi] * x3 + c8[mi] * x4; \
    } \
    *(uint4*)(&As[ab][awe]) = make_uint4(pkbf(ym[0], ym[1]), pkbf(ym[2], ym[3]), \
                                         pkbf(ym[4], ym[5]), pkbf(ym[6], ym[7])); \
  } while (0)

  // ---- MFMA geometry: 8 waves as 2x4 grid of 32x128 wave-tiles ----
  const int wr = wave >> 2, wc = wave & 3;
  const int fm = lane & 15;
  const int fkswz = (((lane >> 4) ^ ((lane >> 1) & 3)) << 3);

  f32x4 acc[2][8] = {};

#define COMPUTE(ab, lb) do { \
    bf16x8 af[2], bfv[8]; \
    _Pragma("unroll") \
    for (int t2 = 0; t2 < 2; ++t2) \
      af[t2] = *(const bf16x8*)&As[ab][(wr * 32 + t2 * 16 + fm) * BK + fkswz]; \
    _Pragma("unroll") \
    for (int u = 0; u < 8; ++u) \
      bfv[u] = *(const bf16x8*)&Bs[lb][(wc * 128 + u * 16 + fm) * BK + fkswz]; \
    __builtin_amdgcn_s_setprio(1); \
    _Pragma("unroll") \
    for (int mt = 0; mt < 2; ++mt) \
      _Pragma("unroll") \
      for (int nt = 0; nt < 8; ++nt) \
        acc[mt][nt] = __builtin_amdgcn_mfma_f32_16x16x32_bf16(af[mt], bfv[nt], acc[mt][nt], 0, 0, 0); \
    __builtin_amdgcn_s_setprio(0); \
  } while (0)

  // one pipeline step: stage batch t+2; producer waves build As for t+1;
  // all waves compute t; counted vmcnt(4) keeps the new batch in flight.
#define STEP(lbN, ap, ac, lb, t1) do { \
    STAGEB(lbN); \
    if (wave < 4) BASIS(ap, t1); \
    COMPUTE(ac, lb); WAIT_BAR(4); } while (0)

  // ---- prologue ----
  STAGEB(0); STAGEB(1);
  __syncthreads();              // Xs + Bs[0..1] visible (full drain, once)
  if (wave < 4) BASIS(0, 0);
  WAIT_BAR(0);                  // As[0] visible

  // ---- main loop: 62 steps = 10 x unrolled-6 + 2 explicit ----
  for (int tb = 0; tb < 60; tb += 6) {
    STEP(2, 1, 0, 0, tb + 1);   // t = tb+0
    STEP(0, 0, 1, 1, tb + 2);   // t = tb+1
    STEP(1, 1, 0, 2, tb + 3);   // t = tb+2
    STEP(2, 0, 1, 0, tb + 4);   // t = tb+3
    STEP(0, 1, 0, 1, tb + 5);   // t = tb+4
    STEP(1, 0, 1, 2, tb + 6);   // t = tb+5
  }
  STEP(2, 1, 0, 0, 61);         // t = 60
  STEP(0, 0, 1, 1, 62);         // t = 61 (stages batch 63 — all staged)
  // ---- tail K-steps: t = 62, 63 ----
  if (wave < 4) BASIS(1, 63);
  COMPUTE(0, 2);                // t=62: As[0], Bs[62%3=2]
  WAIT_BAR(0);
  COMPUTE(1, 0);                // t=63: As[1], Bs[63%3=0]

  // ---- epilogue: C/D layout col = lane&15, row = (lane>>4)*4 + reg ----
  const int colb = wc * 128 + fm;
  const int rowb = bm * BM + wr * 32 + (lane >> 4) * 4;
  float* out = P + (ATOMIC ? (size_t)0 : (size_t)ks * MN);
  #pragma unroll
  for (int mt = 0; mt < 2; ++mt) {
    #pragma unroll
    for (int nt = 0; nt < 8; ++nt) {
      #pragma unroll
      for (int j = 0; j < 4; ++j) {
        int row = rowb + mt * 16 + j;
        int col = colb + nt * 16;
        float vv = acc[mt][nt][j];
        if (ATOMIC) atomicAdd(out + (size_t)row * OUT_DIM + col, vv);
        else        out[(size_t)row * OUT_DIM + col] = vv;
      }
    }
  }
#undef STAGEB
#undef BASIS
#undef COMPUTE
#undef STEP
}

// ---------- phase 3: reduce split-K partials ----------
__global__ __launch_bounds__(256) void reduce_kernel(
    const float* __restrict__ P, float* __restrict__ out) {
  int i = blockIdx.x * 256 + threadIdx.x;
  const float4* p = (const float4*)P;
  float4 r = p[i];
  #pragma unroll
  for (int s = 1; s < SPLITK; ++s) {
    float4 v = p[i + (size_t)s * (MN / 4)];
    r.x += v.x; r.y += v.y; r.z += v.z; r.w += v.w;
  }
  ((float4*)out)[i] = r;
}

extern "C" void kernel_launch(void* const* d_in, const int* in_sizes, int n_in,
                              void* d_out, int out_size, void* d_ws, size_t ws_size,
                              hipStream_t stream) {
  const float* x      = (const float*)d_in[0];   // [4096][512]
  const float* coeffs = (const float*)d_in[1];   // [512][512][16]
  const float* b_coef = (const float*)d_in[2];   // [16][8]
  float* out = (float*)d_out;
  char*  ws  = (char*)d_ws;

  const size_t COEF_BYTES = (size_t)OUT_DIM * K_DIM * 2;   // 8 MiB
  ushort_t* coefb = (ushort_t*)ws;
  float* partials = (float*)(ws + COEF_BYTES);
  const size_t FULL = COEF_BYTES + (size_t)SPLITK * MN * 4;  // 40 MiB
  const bool use_atomic = (ws_size < FULL);   // deterministic per-session branch

  convert_coeffs_kernel<<<CONV_N4 / 256, 256, 0, stream>>>(coeffs, coefb);

  const int nblk = (B_DIM / BM) * SPLITK;   // 64 x 4 = 256 blocks, 1/CU
  if (use_atomic) {
    hipMemsetAsync(d_out, 0, (size_t)MN * 4, stream);
    gemm_kernel<1><<<nblk, 512, 0, stream>>>(x, coefb, b_coef, out);
  } else {
    gemm_kernel<0><<<nblk, 512, 0, stream>>>(x, coefb, b_coef, partials);
    reduce_kernel<<<MN / 4 / 256, 256, 0, stream>>>(partials, out);
  }
}